// Round 4
// baseline (155.072 us; speedup 1.0000x reference)
//
#include <hip/hip_runtime.h>

#define HH 1024
#define WW 1024
#define NB 16
#define TR 8                        // output rows per block
#define NBLK (NB * (HH / TR))       // 2048 blocks
#define NELEM ((long long)NB * HH * WW)

// Load an 8-float stencil window [c0-2 .. c0+5] of global row (gy) into 8
// NAMED SCALARS p0..p7 (no arrays anywhere -> SROA cannot fail -> no scratch;
// R2's 20.5 MB WRITE_SIZE was exactly this failure). Row bounds branch is
// block-uniform; out-of-image rows are the reference zero pad. Values and
// zero-fix order are bit-identical to the R0 LDS path.
#define GWIN(gy, p) \
    float p##0, p##1, p##2, p##3, p##4, p##5, p##6, p##7; \
    { const int _gy = (gy); \
      if (_gy >= 0 && _gy < HH) { \
        const float* _r = ybase + _gy * WW; \
        float2 _L = *(const float2*)(_r + (ledge ? c0 : c0 - 2)); \
        float4 _M = *(const float4*)(_r + c0); \
        float2 _R = *(const float2*)(_r + (redge ? c0 : c0 + 4)); \
        if (ledge) { _L.x = 0.f; _L.y = 0.f; } \
        if (redge) { _R.x = 0.f; _R.y = 0.f; } \
        p##0 = _L.x; p##1 = _L.y; p##2 = _M.x; p##3 = _M.y; \
        p##4 = _M.z; p##5 = _M.w; p##6 = _R.x; p##7 = _R.y; \
      } else { \
        p##0 = 0.f; p##1 = 0.f; p##2 = 0.f; p##3 = 0.f; \
        p##4 = 0.f; p##5 = 0.f; p##6 = 0.f; p##7 = 0.f; } }

// One output element. Math and op order identical to R0 (absmax 0.0):
// max|c-nb| = max(max(nb)-c, c-min(nb)); folds to v_max3/v_min3.
// log1p(-c) == log(1-c) exactly in fp32 for c in [0.5,1) (Sterbenz).
#define COL(al, am, ar, bl, bm, br, cl, cm, cr, tt) { \
    const float c   = bm; \
    const float mxA = fmaxf(fmaxf(al, am), ar); \
    const float mxB = fmaxf(bl, br); \
    const float mxC = fmaxf(fmaxf(cl, cm), cr); \
    const float mx  = fmaxf(fmaxf(mxA, mxB), mxC); \
    const float mnA = fminf(fminf(al, am), ar); \
    const float mnB = fminf(bl, br); \
    const float mnC = fminf(fminf(cl, cm), cr); \
    const float mn  = fminf(fminf(mnA, mnB), mnC); \
    const float w   = fmaxf(mx - c, c - mn); \
    const float lp  = fmaxf(__logf(c), -100.f); \
    const float l1p = fmaxf(__logf(1.f - c), -100.f); \
    const float th  = (c >= 0.5f) ? c : 0.f; \
    sum += w * th - l1p - (tt) * (lp - l1p); }

// One output row k: windows A (row k-2), B (row k), C (row k+2), j = 0..3.
#define ROW4(A, B, C, k) { \
    const float4 _t = *(const float4*)(tbase + (k) * WW + c0); \
    COL(A##0, A##2, A##4, B##0, B##2, B##4, C##0, C##2, C##4, _t.x); \
    COL(A##1, A##3, A##5, B##1, B##3, B##5, C##1, C##3, C##5, _t.y); \
    COL(A##2, A##4, A##6, B##2, B##4, B##6, C##2, C##4, C##6, _t.z); \
    COL(A##3, A##5, A##7, B##3, B##5, B##7, C##3, C##5, C##7, _t.w); }

// Pure register pipeline: no data LDS, no barrier, no arrays. Each of the 12
// involved y_pred rows is loaded exactly once per thread (SSA windows, rolled
// by liveness). Global loads sit far ahead of their use so the compiler can
// prefetch within the 128-VGPR budget.
__global__ __launch_bounds__(256, 4) void closs_main(const float* __restrict__ yt,
                                                     const float* __restrict__ yp,
                                                     float* __restrict__ partial) {
    const int bid  = blockIdx.x;
    const int img  = bid >> 7;          // 128 tiles per image
    const int tile = bid & 127;
    const int y0   = tile * TR;
    const int tid  = threadIdx.x;
    const int c0   = tid << 2;          // 4 columns per thread

    const bool ledge = (tid == 0);
    const bool redge = (tid == 255);

    const float* __restrict__ ybase = yp + (long long)img * (HH * WW);
    const float* __restrict__ tbase = yt + ((long long)img * HH + y0) * WW;

    float sum = 0.f;

    GWIN(y0 - 2, ra)                    // rows y0-2 .. y0+9, one window each
    GWIN(y0 - 1, rb)
    GWIN(y0 + 0, rc)
    GWIN(y0 + 1, rd)
    GWIN(y0 + 2, re)
    ROW4(ra, rc, re, 0)
    GWIN(y0 + 3, rf)
    ROW4(rb, rd, rf, 1)
    GWIN(y0 + 4, rg)
    ROW4(rc, re, rg, 2)
    GWIN(y0 + 5, rh)
    ROW4(rd, rf, rh, 3)
    GWIN(y0 + 6, ri)
    ROW4(re, rg, ri, 4)
    GWIN(y0 + 7, rj)
    ROW4(rf, rh, rj, 5)
    GWIN(y0 + 8, rk)
    ROW4(rg, ri, rk, 6)
    GWIN(y0 + 9, rl)
    ROW4(rh, rj, rl, 7)

    // Block reduction -> one partial write (no atomics: R4 proved 16K
    // same-address atomicAdds serialize to ~215 us).
    for (int o = 32; o > 0; o >>= 1) sum += __shfl_down(sum, o);
    __shared__ float wsum[4];
    if ((tid & 63) == 0) wsum[tid >> 6] = sum;
    __syncthreads();
    if (tid == 0) partial[bid] = wsum[0] + wsum[1] + wsum[2] + wsum[3];
}

// Final reduction over 2048 partials in one 1024-thread block.
__global__ __launch_bounds__(1024) void closs_reduce(const float* __restrict__ partial,
                                                     float* __restrict__ out) {
    const float2* p2 = (const float2*)partial;    // 1024 float2s
    float2 v = p2[threadIdx.x];
    float s = v.x + v.y;
    for (int o = 32; o > 0; o >>= 1) s += __shfl_down(s, o);
    __shared__ float wsum[16];
    if ((threadIdx.x & 63) == 0) wsum[threadIdx.x >> 6] = s;
    __syncthreads();
    if (threadIdx.x == 0) {
        float t = 0.f;
#pragma unroll
        for (int i = 0; i < 16; ++i) t += wsum[i];
        out[0] = t * (1.0f / (float)NELEM);
    }
}

extern "C" void kernel_launch(void* const* d_in, const int* in_sizes, int n_in,
                              void* d_out, int out_size, void* d_ws, size_t ws_size,
                              hipStream_t stream) {
    const float* y_true = (const float*)d_in[0];
    const float* y_pred = (const float*)d_in[1];
    float* out = (float*)d_out;
    float* partial = (float*)d_ws;   // NBLK*4 = 8 KB scratch

    closs_main<<<NBLK, 256, 0, stream>>>(y_true, y_pred, partial);
    closs_reduce<<<1, 1024, 0, stream>>>(partial, out);
}

// Round 5
// 145.743 us; speedup vs baseline: 1.0640x; 1.0640x over previous
//
#include <hip/hip_runtime.h>

#define HH 1024
#define WW 1024
#define NB 16
#define TR 8                        // output rows per block
#define SR (TR + 4)                 // staged rows: y0-2 .. y0+TR+1
#define NBLK (NB * (HH / TR))       // 2048 blocks
#define NELEM ((long long)NB * HH * WW)

// Read an 8-float stencil window [c0-2 .. c0+5] from an LDS row.
// Lane stride is 16 B -> 2 lanes/bank on all pieces = conflict-free (m136).
__device__ __forceinline__ void lds_win(const float* __restrict__ S, int row,
                                        int c0, bool ledge, bool redge, float w[8]) {
    const float* p = S + row * WW;
    float2 L = *(const float2*)(p + (ledge ? c0 : c0 - 2));
    float4 M = *(const float4*)(p + c0);
    float2 R = *(const float2*)(p + (redge ? c0 : c0 + 4));
    if (ledge) { L.x = 0.f; L.y = 0.f; }
    if (redge) { R.x = 0.f; R.y = 0.f; }
    w[0]=L.x; w[1]=L.y; w[2]=M.x; w[3]=M.y; w[4]=M.z; w[5]=M.w; w[6]=R.x; w[7]=R.y;
}

// R0 structure (12-row LDS stage -> barrier -> pure-LDS compute), but 512
// threads/block: same 48.5 KB LDS still allows 3 blocks/CU, now 3x8 = 24
// waves/CU resident (was 12). Per-thread work halves: threads tid<256 own
// output rows 0-3 of the tile, tid>=256 own rows 4-7; each does 4 rows x
// 4 cols. All memory patterns (coalescing, window reads, math op order)
// identical to the proven 46 us kernel.
__global__ __launch_bounds__(512) void closs_main(const float* __restrict__ yt,
                                                  const float* __restrict__ yp,
                                                  float* __restrict__ partial) {
    __shared__ float S[SR * WW];        // 48 KB -> 3 blocks/CU resident

    const int bid   = blockIdx.x;
    const int img   = bid >> 7;         // 128 tiles per image
    const int tile  = bid & 127;
    const int y0    = tile * TR;
    const int tid   = threadIdx.x;
    const int lane  = tid & 255;        // column group (same role as R0 tid)
    const int rhalf = tid >> 8;         // 0: rows 0-3, 1: rows 4-7
    const int c0    = lane << 2;        // 4 columns per thread

    const float* __restrict__ ybase = yp + (long long)img * (HH * WW);
    const float* __restrict__ tbase = yt + ((long long)img * HH + y0) * WW;

    // Stage SR=12 rows as aligned float4 streams; 6 rows per thread-half
    // (even rows by tid<256, odd rows by tid>=256 -> branch wave-uniform).
    // Rows outside [0,HH) zero-filled == reference zero padding.
#pragma unroll
    for (int ii = 0; ii < 6; ++ii) {
        const int r  = (ii << 1) + rhalf;
        const int gy = y0 - 2 + r;
        float4 v = make_float4(0.f, 0.f, 0.f, 0.f);
        if (gy >= 0 && gy < HH)
            v = *(const float4*)(ybase + gy * WW + c0);
        *(float4*)&S[r * WW + c0] = v;
    }
    __syncthreads();

    const bool ledge = (lane == 0);
    const bool redge = (lane == 255);
    const int  kb    = rhalf << 2;      // first output row of this half

    float sum = 0.f;
#pragma unroll
    for (int k2 = 0; k2 < 4; ++k2) {
        const int k = kb + k2;
        float A[8], B[8], C[8];         // LDS rows k (y-2), k+2 (y), k+4 (y+2)
        lds_win(S, k,     c0, ledge, redge, A);
        lds_win(S, k + 2, c0, ledge, redge, B);
        lds_win(S, k + 4, c0, ledge, redge, C);

        const float4 t4 = *(const float4*)(tbase + k * WW + c0);
        const float tt[4] = {t4.x, t4.y, t4.z, t4.w};

#pragma unroll
        for (int j = 0; j < 4; ++j) {
            const float c = B[j + 2];
            // max|c-nb| = max(max(nb)-c, c-min(nb)); bit-identical to the
            // |diff| chain (absmax 0.0 since R3); folds to v_max3/v_min3.
            const float mxA = fmaxf(fmaxf(A[j], A[j + 2]), A[j + 4]);
            const float mxB = fmaxf(B[j], B[j + 4]);
            const float mxC = fmaxf(fmaxf(C[j], C[j + 2]), C[j + 4]);
            const float mx  = fmaxf(fmaxf(mxA, mxB), mxC);
            const float mnA = fminf(fminf(A[j], A[j + 2]), A[j + 4]);
            const float mnB = fminf(B[j], B[j + 4]);
            const float mnC = fminf(fminf(C[j], C[j + 2]), C[j + 4]);
            const float mn  = fminf(fminf(mnA, mnB), mnC);
            const float w   = fmaxf(mx - c, c - mn);

            // log1p(-c) == log(1-c) exactly in fp32 for c in [0.5,1)
            // (Sterbenz); -100 clamp covers c -> 1 / c == 0.
            const float lp  = fmaxf(__logf(c), -100.f);
            const float l1p = fmaxf(__logf(1.f - c), -100.f);
            const float th  = (c >= 0.5f) ? c : 0.f;
            sum += w * th - l1p - tt[j] * (lp - l1p);
        }
    }

    // Block reduction over 8 waves -> one partial write (no atomics: R4
    // proved 16K same-address atomicAdds serialize to ~215 us).
    for (int o = 32; o > 0; o >>= 1) sum += __shfl_down(sum, o);
    __shared__ float wsum[8];
    if ((tid & 63) == 0) wsum[tid >> 6] = sum;
    __syncthreads();
    if (tid == 0) {
        float t = 0.f;
#pragma unroll
        for (int i = 0; i < 8; ++i) t += wsum[i];
        partial[bid] = t;
    }
}

// Final reduction over 2048 partials in one 1024-thread block.
__global__ __launch_bounds__(1024) void closs_reduce(const float* __restrict__ partial,
                                                     float* __restrict__ out) {
    const float2* p2 = (const float2*)partial;    // 1024 float2s
    float2 v = p2[threadIdx.x];
    float s = v.x + v.y;
    for (int o = 32; o > 0; o >>= 1) s += __shfl_down(s, o);
    __shared__ float wsum[16];
    if ((threadIdx.x & 63) == 0) wsum[threadIdx.x >> 6] = s;
    __syncthreads();
    if (threadIdx.x == 0) {
        float t = 0.f;
#pragma unroll
        for (int i = 0; i < 16; ++i) t += wsum[i];
        out[0] = t * (1.0f / (float)NELEM);
    }
}

extern "C" void kernel_launch(void* const* d_in, const int* in_sizes, int n_in,
                              void* d_out, int out_size, void* d_ws, size_t ws_size,
                              hipStream_t stream) {
    const float* y_true = (const float*)d_in[0];
    const float* y_pred = (const float*)d_in[1];
    float* out = (float*)d_out;
    float* partial = (float*)d_ws;   // NBLK*4 = 8 KB scratch

    closs_main<<<NBLK, 512, 0, stream>>>(y_true, y_pred, partial);
    closs_reduce<<<1, 1024, 0, stream>>>(partial, out);
}